// Round 2
// baseline (342.566 us; speedup 1.0000x reference)
//
#include <hip/hip_runtime.h>

#define D 32
#define STEPSZ 1.0f

// ---------------------------------------------------------------------------
// K1: per-node precompute.  a[n] = x[n].sheafW[0:D], b[n] = x[n].sheafW[D:2D]
//     y[n,:] = lin_W @ x[n] + lin_b
// ---------------------------------------------------------------------------
__global__ void k_node_pre(const float* __restrict__ x,
                           const float* __restrict__ sheafW,
                           const float* __restrict__ linW,
                           const float* __restrict__ linb,
                           float* __restrict__ a, float* __restrict__ b,
                           float* __restrict__ y, int N) {
    __shared__ float sW[D * D];
    __shared__ float sB[D];
    __shared__ float sS[2 * D];
    for (int i = threadIdx.x; i < D * D; i += blockDim.x) sW[i] = linW[i];
    if (threadIdx.x < D) sB[threadIdx.x] = linb[threadIdx.x];
    if (threadIdx.x < 2 * D) sS[threadIdx.x] = sheafW[threadIdx.x];
    __syncthreads();

    int n = blockIdx.x * blockDim.x + threadIdx.x;
    if (n >= N) return;

    float xv[D];
    const float4* xp = reinterpret_cast<const float4*>(x + (size_t)n * D);
#pragma unroll
    for (int i = 0; i < D / 4; ++i) {
        float4 v = xp[i];
        xv[4 * i + 0] = v.x; xv[4 * i + 1] = v.y;
        xv[4 * i + 2] = v.z; xv[4 * i + 3] = v.w;
    }

    float av = 0.f, bv = 0.f;
#pragma unroll
    for (int d = 0; d < D; ++d) { av += xv[d] * sS[d]; bv += xv[d] * sS[D + d]; }
    a[n] = av;
    b[n] = bv;

    float4* yp = reinterpret_cast<float4*>(y + (size_t)n * D);
#pragma unroll
    for (int j4 = 0; j4 < D / 4; ++j4) {
        float4 o;
#pragma unroll
        for (int jj = 0; jj < 4; ++jj) {
            int j = 4 * j4 + jj;
            float s = sB[j];
#pragma unroll
            for (int d = 0; d < D; ++d) s += xv[d] * sW[j * D + d];
            (&o.x)[jj] = s;
        }
        yp[j4] = o;
    }
}

// ---------------------------------------------------------------------------
// K2: per-edge pass 1 — diag segment-sum + degree histogram.
// ---------------------------------------------------------------------------
__global__ void k_edge_pass1(const int* __restrict__ ei,
                             const float* __restrict__ a,
                             const float* __restrict__ b,
                             float* __restrict__ diag_maps,
                             int* __restrict__ cnt, int E) {
    int e = blockIdx.x * blockDim.x + threadIdx.x;
    if (e >= E) return;
    int row = ei[e];
    int col = ei[E + e];
    float m = tanhf(a[row] + b[col]);
    atomicAdd(&diag_maps[row], m * m);
    atomicAdd(&cnt[row], 1);
}

// ---------------------------------------------------------------------------
// Scan level 1: per-block (256 elems) exclusive scan of cnt -> off, blocksums.
// ---------------------------------------------------------------------------
__global__ void k_scan1(const int* __restrict__ cnt, int* __restrict__ off,
                        int* __restrict__ bsum, int N) {
    __shared__ int s[256];
    int t = threadIdx.x;
    int i = blockIdx.x * 256 + t;
    int v = (i < N) ? cnt[i] : 0;
    s[t] = v;
    __syncthreads();
#pragma unroll
    for (int o = 1; o < 256; o <<= 1) {
        int tmp = (t >= o) ? s[t - o] : 0;
        __syncthreads();
        s[t] += tmp;
        __syncthreads();
    }
    if (i < N) off[i] = s[t] - v;           // local exclusive
    if (t == 255) bsum[blockIdx.x] = s[255];
}

// ---------------------------------------------------------------------------
// Scan level 2: single block scans the block sums (<=256 of them) in place
// to EXCLUSIVE block offsets.
// ---------------------------------------------------------------------------
__global__ void k_scan2(int* __restrict__ bsum, int NB) {
    __shared__ int s[256];
    int t = threadIdx.x;
    int v = (t < NB) ? bsum[t] : 0;
    s[t] = v;
    __syncthreads();
#pragma unroll
    for (int o = 1; o < 256; o <<= 1) {
        int tmp = (t >= o) ? s[t - o] : 0;
        __syncthreads();
        s[t] += tmp;
        __syncthreads();
    }
    if (t < NB) bsum[t] = s[t] - v;         // exclusive
}

// ---------------------------------------------------------------------------
// Scan level 3 + node scalars: finalize offsets, init cursor, dsi/diag.
// ---------------------------------------------------------------------------
__global__ void k_scan3(int* __restrict__ off, int* __restrict__ cursor,
                        const int* __restrict__ bsum,
                        const float* __restrict__ diag_maps,
                        float* __restrict__ dsi, float* __restrict__ diag,
                        int N) {
    int n = blockIdx.x * blockDim.x + threadIdx.x;
    if (n >= N) return;
    int o = off[n] + bsum[n >> 8];
    off[n] = o;
    cursor[n] = o;
    float dm = diag_maps[n];
    float ds = rsqrtf(dm + 1.0f);
    dsi[n] = ds;
    diag[n] = dm * ds * ds;
}

// ---------------------------------------------------------------------------
// K4: CSR fill. Reverse edge of (row,col) is (col,row), so the reverse map is
// computed analytically: mr = tanh(a[col]+b[row]).  val = m*mr*dsi[col].
// ---------------------------------------------------------------------------
__global__ void k_fill(const int* __restrict__ ei,
                       const float* __restrict__ a,
                       const float* __restrict__ b,
                       const float* __restrict__ dsi,
                       int* __restrict__ cursor,
                       int2* __restrict__ pairs, int E) {
    int e = blockIdx.x * blockDim.x + threadIdx.x;
    if (e >= E) return;
    int row = ei[e];
    int col = ei[E + e];
    float m  = tanhf(a[row] + b[col]);
    float mr = tanhf(a[col] + b[row]);
    float val = m * mr * dsi[col];
    int pos = atomicAdd(&cursor[row], 1);
    pairs[pos] = make_int2(col, __float_as_int(val));
}

// ---------------------------------------------------------------------------
// K5: gather + finalize. Half-wave (32 lanes == D) per node.
//     out = x - diag*y + dsi[n] * sum_k val_k * y[col_k,:]
// ---------------------------------------------------------------------------
__global__ void k_gather(const int* __restrict__ off,
                         const int* __restrict__ cnt,
                         const int2* __restrict__ pairs,
                         const float* __restrict__ y,
                         const float* __restrict__ x,
                         const float* __restrict__ dsi,
                         const float* __restrict__ diag,
                         float* __restrict__ out, int N) {
    int t = blockIdx.x * blockDim.x + threadIdx.x;
    int n = t >> 5;
    int lane = t & 31;
    if (n >= N) return;
    int start = off[n];
    int deg = cnt[n];
    float acc = 0.f;
    for (int k = 0; k < deg; ++k) {
        int2 p = pairs[start + k];                       // uniform 8B load
        acc += __int_as_float(p.y) * y[(size_t)p.x * D + lane];
    }
    float yv = y[t];
    out[t] = x[t] - STEPSZ * (diag[n] * yv - dsi[n] * acc);
}

extern "C" void kernel_launch(void* const* d_in, const int* in_sizes, int n_in,
                              void* d_out, int out_size, void* d_ws, size_t ws_size,
                              hipStream_t stream) {
    const float* x      = (const float*)d_in[0];
    const float* sheafW = (const float*)d_in[1];
    const float* linW   = (const float*)d_in[2];
    const float* linb   = (const float*)d_in[3];
    const int*   ei     = (const int*)d_in[4];

    int N = in_sizes[0] / D;
    int E = in_sizes[4] / 2;

    // Workspace layout (4B elements):
    // y[N*D] | pairs[E x int2] | a[N] b[N] diag_maps[N] cnt[N] off[N] cursor[N]
    // dsi[N] diag[N] bsum[256]
    float* ws   = (float*)d_ws;
    float* y    = ws;
    int2*  pairs = (int2*)(ws + (size_t)N * D);
    float* a    = ws + (size_t)N * D + 2 * (size_t)E;
    float* b    = a + N;
    float* diag_maps = b + N;
    int*   cnt  = (int*)(diag_maps + N);
    int*   off  = cnt + N;
    int*   cursor = off + N;
    float* dsi  = (float*)(cursor + N);
    float* diag = dsi + N;
    int*   bsum = (int*)(diag + N);

    float* out = (float*)d_out;

    // zero diag_maps and cnt (adjacent) in one memset
    hipMemsetAsync(diag_maps, 0, 2 * (size_t)N * sizeof(float), stream);

    const int B = 256;
    int nbN = (N + B - 1) / B;      // 196 for N=50000
    int nbE = (E + B - 1) / B;

    k_node_pre<<<nbN, B, 0, stream>>>(x, sheafW, linW, linb, a, b, y, N);
    k_edge_pass1<<<nbE, B, 0, stream>>>(ei, a, b, diag_maps, cnt, E);
    k_scan1<<<nbN, B, 0, stream>>>(cnt, off, bsum, N);
    k_scan2<<<1, B, 0, stream>>>(bsum, nbN);
    k_scan3<<<nbN, B, 0, stream>>>(off, cursor, bsum, diag_maps, dsi, diag, N);
    k_fill<<<nbE, B, 0, stream>>>(ei, a, b, dsi, cursor, pairs, E);
    k_gather<<<((size_t)N * D + B - 1) / B, B, 0, stream>>>(off, cnt, pairs, y, x, dsi, diag, out, N);
}

// Round 3
// 173.711 us; speedup vs baseline: 1.9720x; 1.9720x over previous
//
#include <hip/hip_runtime.h>

#define D 32
#define STEPSZ 1.0f

#define FIX_SHIFT 30            // fixed-point scale for m^2 in low bits
#define CNT_SHIFT 44            // degree count lives in bits [44,64)
#define FIX_MASK ((1ULL << CNT_SHIFT) - 1)

// ---------------------------------------------------------------------------
// K1: per-node precompute.  a[n] = x[n].sheafW[0:D], b[n] = x[n].sheafW[D:2D]
//     y[n,:] = lin_W @ x[n] + lin_b
// ---------------------------------------------------------------------------
__global__ void k_node_pre(const float* __restrict__ x,
                           const float* __restrict__ sheafW,
                           const float* __restrict__ linW,
                           const float* __restrict__ linb,
                           float* __restrict__ a, float* __restrict__ b,
                           float* __restrict__ y, int N) {
    __shared__ float sW[D * D];
    __shared__ float sB[D];
    __shared__ float sS[2 * D];
    for (int i = threadIdx.x; i < D * D; i += blockDim.x) sW[i] = linW[i];
    if (threadIdx.x < D) sB[threadIdx.x] = linb[threadIdx.x];
    if (threadIdx.x < 2 * D) sS[threadIdx.x] = sheafW[threadIdx.x];
    __syncthreads();

    int n = blockIdx.x * blockDim.x + threadIdx.x;
    if (n >= N) return;

    float xv[D];
    const float4* xp = reinterpret_cast<const float4*>(x + (size_t)n * D);
#pragma unroll
    for (int i = 0; i < D / 4; ++i) {
        float4 v = xp[i];
        xv[4 * i + 0] = v.x; xv[4 * i + 1] = v.y;
        xv[4 * i + 2] = v.z; xv[4 * i + 3] = v.w;
    }

    float av = 0.f, bv = 0.f;
#pragma unroll
    for (int d = 0; d < D; ++d) { av += xv[d] * sS[d]; bv += xv[d] * sS[D + d]; }
    a[n] = av;
    b[n] = bv;

    float4* yp = reinterpret_cast<float4*>(y + (size_t)n * D);
#pragma unroll
    for (int j4 = 0; j4 < D / 4; ++j4) {
        float4 o;
#pragma unroll
        for (int jj = 0; jj < 4; ++jj) {
            int j = 4 * j4 + jj;
            float s = sB[j];
#pragma unroll
            for (int d = 0; d < D; ++d) s += xv[d] * sW[j * D + d];
            (&o.x)[jj] = s;
        }
        yp[j4] = o;
    }
}

// ---------------------------------------------------------------------------
// K2: one thread per UNDIRECTED pair i (covers directed edges i and i+E2).
//     One u64 atomic per directed edge packs {degree count | fixed-point m^2}.
//     Returned old value's high bits = this edge's rank within its row.
// ---------------------------------------------------------------------------
__global__ void k_edge_pass1(const int* __restrict__ ei,
                             const float* __restrict__ a,
                             const float* __restrict__ b,
                             unsigned long long* __restrict__ diagcnt,
                             unsigned short* __restrict__ rank,
                             float* __restrict__ mm, int E2, int E) {
    int i = blockIdx.x * blockDim.x + threadIdx.x;
    if (i >= E2) return;
    int s = ei[i];          // row of edge i
    int t = ei[E + i];      // col of edge i  (edge i+E2 is (t,s))
    float as = a[s], bs = b[s], at = a[t], bt = b[t];
    float m  = tanhf(as + bt);
    float mr = tanhf(at + bs);

    unsigned long long add_s = (1ULL << CNT_SHIFT) |
        (unsigned long long)(m * m * (float)(1 << FIX_SHIFT));
    unsigned long long add_t = (1ULL << CNT_SHIFT) |
        (unsigned long long)(mr * mr * (float)(1 << FIX_SHIFT));

    unsigned long long old_s = atomicAdd(&diagcnt[s], add_s);
    unsigned long long old_t = atomicAdd(&diagcnt[t], add_t);

    rank[i]      = (unsigned short)(old_s >> CNT_SHIFT);
    rank[i + E2] = (unsigned short)(old_t >> CNT_SHIFT);
    mm[i] = m * mr;
}

// ---------------------------------------------------------------------------
// Scan level 1: per-block (256) exclusive scan of degree counts -> off, bsum.
// ---------------------------------------------------------------------------
__global__ void k_scan1(const unsigned long long* __restrict__ diagcnt,
                        int* __restrict__ off, int* __restrict__ bsum, int N) {
    __shared__ int s[256];
    int t = threadIdx.x;
    int i = blockIdx.x * 256 + t;
    int v = (i < N) ? (int)(diagcnt[i] >> CNT_SHIFT) : 0;
    s[t] = v;
    __syncthreads();
#pragma unroll
    for (int o = 1; o < 256; o <<= 1) {
        int tmp = (t >= o) ? s[t - o] : 0;
        __syncthreads();
        s[t] += tmp;
        __syncthreads();
    }
    if (i < N) off[i] = s[t] - v;           // local exclusive
    if (t == 255) bsum[blockIdx.x] = s[255];
}

// ---------------------------------------------------------------------------
// Scan level 2: single block scans the block sums (<=256) to exclusive.
// ---------------------------------------------------------------------------
__global__ void k_scan2(int* __restrict__ bsum, int NB) {
    __shared__ int s[256];
    int t = threadIdx.x;
    int v = (t < NB) ? bsum[t] : 0;
    s[t] = v;
    __syncthreads();
#pragma unroll
    for (int o = 1; o < 256; o <<= 1) {
        int tmp = (t >= o) ? s[t - o] : 0;
        __syncthreads();
        s[t] += tmp;
        __syncthreads();
    }
    if (t < NB) bsum[t] = s[t] - v;         // exclusive
}

// ---------------------------------------------------------------------------
// Scan level 3 + node scalars: finalize offsets, dsi/diag from packed bits.
// ---------------------------------------------------------------------------
__global__ void k_scan3(int* __restrict__ off, const int* __restrict__ bsum,
                        const unsigned long long* __restrict__ diagcnt,
                        float* __restrict__ dsi, float* __restrict__ diag,
                        int N, int E) {
    int n = blockIdx.x * blockDim.x + threadIdx.x;
    if (n >= N) return;
    off[n] = off[n] + bsum[n >> 8];
    if (n == 0) off[N] = E;
    float dm = (float)(double)(diagcnt[n] & FIX_MASK) *
               (1.0f / (float)(1 << FIX_SHIFT));
    float ds = rsqrtf(dm + 1.0f);
    dsi[n] = ds;
    diag[n] = dm * ds * ds;
}

// ---------------------------------------------------------------------------
// K4: CSR fill — atomic-free. pos = off[row] + rank[e].
// ---------------------------------------------------------------------------
__global__ void k_fill(const int* __restrict__ ei,
                       const float* __restrict__ mm,
                       const float* __restrict__ dsi,
                       const int* __restrict__ off,
                       const unsigned short* __restrict__ rank,
                       int2* __restrict__ pairs, int E2, int E) {
    int e = blockIdx.x * blockDim.x + threadIdx.x;
    if (e >= E) return;
    int row = ei[e];
    int col = ei[E + e];
    float val = mm[e < E2 ? e : e - E2] * dsi[col];
    int pos = off[row] + (int)rank[e];
    pairs[pos] = make_int2(col, __float_as_int(val));
}

// ---------------------------------------------------------------------------
// K5: gather + finalize. Half-wave (32 lanes == D) per node.
//     out = x - diag*y + dsi[n] * sum_k val_k * y[col_k,:]
// ---------------------------------------------------------------------------
__global__ void k_gather(const int* __restrict__ off,
                         const int2* __restrict__ pairs,
                         const float* __restrict__ y,
                         const float* __restrict__ x,
                         const float* __restrict__ dsi,
                         const float* __restrict__ diag,
                         float* __restrict__ out, int N) {
    int t = blockIdx.x * blockDim.x + threadIdx.x;
    int n = t >> 5;
    int lane = t & 31;
    if (n >= N) return;
    int start = off[n];
    int end = off[n + 1];
    float acc = 0.f;
    int k = start;
    for (; k + 4 <= end; k += 4) {
        int2 p0 = pairs[k + 0];
        int2 p1 = pairs[k + 1];
        int2 p2 = pairs[k + 2];
        int2 p3 = pairs[k + 3];
        float v0 = y[(size_t)p0.x * D + lane];
        float v1 = y[(size_t)p1.x * D + lane];
        float v2 = y[(size_t)p2.x * D + lane];
        float v3 = y[(size_t)p3.x * D + lane];
        acc += __int_as_float(p0.y) * v0;
        acc += __int_as_float(p1.y) * v1;
        acc += __int_as_float(p2.y) * v2;
        acc += __int_as_float(p3.y) * v3;
    }
    for (; k < end; ++k) {
        int2 p = pairs[k];
        acc += __int_as_float(p.y) * y[(size_t)p.x * D + lane];
    }
    float yv = y[t];
    out[t] = x[t] - STEPSZ * (diag[n] * yv - dsi[n] * acc);
}

extern "C" void kernel_launch(void* const* d_in, const int* in_sizes, int n_in,
                              void* d_out, int out_size, void* d_ws, size_t ws_size,
                              hipStream_t stream) {
    const float* x      = (const float*)d_in[0];
    const float* sheafW = (const float*)d_in[1];
    const float* linW   = (const float*)d_in[2];
    const float* linb   = (const float*)d_in[3];
    const int*   ei     = (const int*)d_in[4];

    int N  = in_sizes[0] / D;
    int E  = in_sizes[4] / 2;
    int E2 = E / 2;

    // Workspace layout (8B-aligned first):
    // diagcnt[N] u64 | pairs[E] int2 | y[N*D] f32 | a[N] b[N] | mm[E2] |
    // off[N+1] | dsi[N] diag[N] | bsum[256] | rank[E] u16
    char* wp = (char*)d_ws;
    unsigned long long* diagcnt = (unsigned long long*)wp; wp += (size_t)N * 8;
    int2*  pairs = (int2*)wp;  wp += (size_t)E * 8;
    float* y     = (float*)wp; wp += (size_t)N * D * 4;
    float* a     = (float*)wp; wp += (size_t)N * 4;
    float* b     = (float*)wp; wp += (size_t)N * 4;
    float* mm    = (float*)wp; wp += (size_t)E2 * 4;
    int*   off   = (int*)wp;   wp += (size_t)(N + 1) * 4;
    float* dsi   = (float*)wp; wp += (size_t)N * 4;
    float* diag  = (float*)wp; wp += (size_t)N * 4;
    int*   bsum  = (int*)wp;   wp += 256 * 4;
    unsigned short* rank = (unsigned short*)wp;

    float* out = (float*)d_out;

    hipMemsetAsync(diagcnt, 0, (size_t)N * sizeof(unsigned long long), stream);

    const int B = 256;
    int nbN  = (N + B - 1) / B;      // 196 for N=50000 (<=256 required by scan2)
    int nbE  = (E + B - 1) / B;
    int nbE2 = (E2 + B - 1) / B;

    k_node_pre<<<nbN, B, 0, stream>>>(x, sheafW, linW, linb, a, b, y, N);
    k_edge_pass1<<<nbE2, B, 0, stream>>>(ei, a, b, diagcnt, rank, mm, E2, E);
    k_scan1<<<nbN, B, 0, stream>>>(diagcnt, off, bsum, N);
    k_scan2<<<1, B, 0, stream>>>(bsum, nbN);
    k_scan3<<<nbN, B, 0, stream>>>(off, bsum, diagcnt, dsi, diag, N, E);
    k_fill<<<nbE, B, 0, stream>>>(ei, mm, dsi, off, rank, pairs, E2, E);
    k_gather<<<((size_t)N * D + B - 1) / B, B, 0, stream>>>(off, pairs, y, x, dsi, diag, out, N);
}

// Round 4
// 170.064 us; speedup vs baseline: 2.0143x; 1.0214x over previous
//
#include <hip/hip_runtime.h>

#define D 32
#define STEPSZ 1.0f

#define FIX_SHIFT 30            // fixed-point scale for m^2 in low bits
#define CNT_SHIFT 44            // degree count lives in bits [44,64)
#define FIX_MASK ((1ULL << CNT_SHIFT) - 1)
#define PAD 8                   // one node per 64B line in diagcnt

// ---------------------------------------------------------------------------
// K1: per-node precompute.  a[n] = x[n].sheafW[0:D], b[n] = x[n].sheafW[D:2D]
//     y[n,:] = lin_W @ x[n] + lin_b
// ---------------------------------------------------------------------------
__global__ void k_node_pre(const float* __restrict__ x,
                           const float* __restrict__ sheafW,
                           const float* __restrict__ linW,
                           const float* __restrict__ linb,
                           float* __restrict__ a, float* __restrict__ b,
                           float* __restrict__ y, int N) {
    __shared__ float sW[D * D];
    __shared__ float sB[D];
    __shared__ float sS[2 * D];
    for (int i = threadIdx.x; i < D * D; i += blockDim.x) sW[i] = linW[i];
    if (threadIdx.x < D) sB[threadIdx.x] = linb[threadIdx.x];
    if (threadIdx.x < 2 * D) sS[threadIdx.x] = sheafW[threadIdx.x];
    __syncthreads();

    int n = blockIdx.x * blockDim.x + threadIdx.x;
    if (n >= N) return;

    float xv[D];
    const float4* xp = reinterpret_cast<const float4*>(x + (size_t)n * D);
#pragma unroll
    for (int i = 0; i < D / 4; ++i) {
        float4 v = xp[i];
        xv[4 * i + 0] = v.x; xv[4 * i + 1] = v.y;
        xv[4 * i + 2] = v.z; xv[4 * i + 3] = v.w;
    }

    float av = 0.f, bv = 0.f;
#pragma unroll
    for (int d = 0; d < D; ++d) { av += xv[d] * sS[d]; bv += xv[d] * sS[D + d]; }
    a[n] = av;
    b[n] = bv;

    float4* yp = reinterpret_cast<float4*>(y + (size_t)n * D);
#pragma unroll
    for (int j4 = 0; j4 < D / 4; ++j4) {
        float4 o;
#pragma unroll
        for (int jj = 0; jj < 4; ++jj) {
            int j = 4 * j4 + jj;
            float s = sB[j];
#pragma unroll
            for (int d = 0; d < D; ++d) s += xv[d] * sW[j * D + d];
            (&o.x)[jj] = s;
        }
        yp[j4] = o;
    }
}

// ---------------------------------------------------------------------------
// K2: one thread per UNDIRECTED pair i (covers directed edges i and i+E2).
//     One u64 atomic per directed edge packs {degree count | fixed-point m^2}.
//     diagcnt is padded: one node per 64B line to break per-line RMW chains.
// ---------------------------------------------------------------------------
__global__ void k_edge_pass1(const int* __restrict__ ei,
                             const float* __restrict__ a,
                             const float* __restrict__ b,
                             unsigned long long* __restrict__ diagcnt,
                             unsigned short* __restrict__ rank,
                             float* __restrict__ mm, int E2, int E) {
    int i = blockIdx.x * blockDim.x + threadIdx.x;
    if (i >= E2) return;
    int s = ei[i];          // row of edge i
    int t = ei[E + i];      // col of edge i  (edge i+E2 is (t,s))
    float as = a[s], bs = b[s], at = a[t], bt = b[t];
    float m  = tanhf(as + bt);
    float mr = tanhf(at + bs);

    unsigned long long add_s = (1ULL << CNT_SHIFT) |
        (unsigned long long)(m * m * (float)(1 << FIX_SHIFT));
    unsigned long long add_t = (1ULL << CNT_SHIFT) |
        (unsigned long long)(mr * mr * (float)(1 << FIX_SHIFT));

    unsigned long long old_s = atomicAdd(&diagcnt[(size_t)s * PAD], add_s);
    unsigned long long old_t = atomicAdd(&diagcnt[(size_t)t * PAD], add_t);

    rank[i]      = (unsigned short)(old_s >> CNT_SHIFT);
    rank[i + E2] = (unsigned short)(old_t >> CNT_SHIFT);
    mm[i] = m * mr;
}

// ---------------------------------------------------------------------------
// Scan level 1: per-block (256) exclusive scan of degree counts -> off, bsum.
// ---------------------------------------------------------------------------
__global__ void k_scan1(const unsigned long long* __restrict__ diagcnt,
                        int* __restrict__ off, int* __restrict__ bsum, int N) {
    __shared__ int s[256];
    int t = threadIdx.x;
    int i = blockIdx.x * 256 + t;
    int v = (i < N) ? (int)(diagcnt[(size_t)i * PAD] >> CNT_SHIFT) : 0;
    s[t] = v;
    __syncthreads();
#pragma unroll
    for (int o = 1; o < 256; o <<= 1) {
        int tmp = (t >= o) ? s[t - o] : 0;
        __syncthreads();
        s[t] += tmp;
        __syncthreads();
    }
    if (i < N) off[i] = s[t] - v;           // local exclusive
    if (t == 255) bsum[blockIdx.x] = s[255];
}

// ---------------------------------------------------------------------------
// Scan level 2: single block scans the block sums (<=256) to exclusive.
// ---------------------------------------------------------------------------
__global__ void k_scan2(int* __restrict__ bsum, int NB) {
    __shared__ int s[256];
    int t = threadIdx.x;
    int v = (t < NB) ? bsum[t] : 0;
    s[t] = v;
    __syncthreads();
#pragma unroll
    for (int o = 1; o < 256; o <<= 1) {
        int tmp = (t >= o) ? s[t - o] : 0;
        __syncthreads();
        s[t] += tmp;
        __syncthreads();
    }
    if (t < NB) bsum[t] = s[t] - v;         // exclusive
}

// ---------------------------------------------------------------------------
// Scan level 3 + node scalars: finalize offsets, dsi/diag from packed bits.
// ---------------------------------------------------------------------------
__global__ void k_scan3(int* __restrict__ off, const int* __restrict__ bsum,
                        const unsigned long long* __restrict__ diagcnt,
                        float* __restrict__ dsi, float* __restrict__ diag,
                        int N, int E) {
    int n = blockIdx.x * blockDim.x + threadIdx.x;
    if (n >= N) return;
    off[n] = off[n] + bsum[n >> 8];
    if (n == 0) off[N] = E;
    float dm = (float)(double)(diagcnt[(size_t)n * PAD] & FIX_MASK) *
               (1.0f / (float)(1 << FIX_SHIFT));
    float ds = rsqrtf(dm + 1.0f);
    dsi[n] = ds;
    diag[n] = dm * ds * ds;
}

// ---------------------------------------------------------------------------
// K4: CSR fill — atomic-free, pair-level (writes both directed entries).
// ---------------------------------------------------------------------------
__global__ void k_fill(const int* __restrict__ ei,
                       const float* __restrict__ mm,
                       const float* __restrict__ dsi,
                       const int* __restrict__ off,
                       const unsigned short* __restrict__ rank,
                       int2* __restrict__ pairs, int E2, int E) {
    int i = blockIdx.x * blockDim.x + threadIdx.x;
    if (i >= E2) return;
    int s = ei[i];
    int t = ei[E + i];
    float v = mm[i];
    float ds_s = dsi[s], ds_t = dsi[t];
    int pos_s = off[s] + (int)rank[i];
    int pos_t = off[t] + (int)rank[i + E2];
    pairs[pos_s] = make_int2(t, __float_as_int(v * ds_t));
    pairs[pos_t] = make_int2(s, __float_as_int(v * ds_s));
}

// ---------------------------------------------------------------------------
// K5: gather + finalize. Half-wave (32 lanes == D) per node.
//     out = x - diag*y + dsi[n] * sum_k val_k * y[col_k,:]
// ---------------------------------------------------------------------------
__global__ void k_gather(const int* __restrict__ off,
                         const int2* __restrict__ pairs,
                         const float* __restrict__ y,
                         const float* __restrict__ x,
                         const float* __restrict__ dsi,
                         const float* __restrict__ diag,
                         float* __restrict__ out, int N) {
    int t = blockIdx.x * blockDim.x + threadIdx.x;
    int n = t >> 5;
    int lane = t & 31;
    if (n >= N) return;
    int start = off[n];
    int end = off[n + 1];
    float acc = 0.f;
    int k = start;
    for (; k + 4 <= end; k += 4) {
        int2 p0 = pairs[k + 0];
        int2 p1 = pairs[k + 1];
        int2 p2 = pairs[k + 2];
        int2 p3 = pairs[k + 3];
        float v0 = y[(size_t)p0.x * D + lane];
        float v1 = y[(size_t)p1.x * D + lane];
        float v2 = y[(size_t)p2.x * D + lane];
        float v3 = y[(size_t)p3.x * D + lane];
        acc += __int_as_float(p0.y) * v0;
        acc += __int_as_float(p1.y) * v1;
        acc += __int_as_float(p2.y) * v2;
        acc += __int_as_float(p3.y) * v3;
    }
    for (; k < end; ++k) {
        int2 p = pairs[k];
        acc += __int_as_float(p.y) * y[(size_t)p.x * D + lane];
    }
    float yv = y[t];
    out[t] = x[t] - STEPSZ * (diag[n] * yv - dsi[n] * acc);
}

extern "C" void kernel_launch(void* const* d_in, const int* in_sizes, int n_in,
                              void* d_out, int out_size, void* d_ws, size_t ws_size,
                              hipStream_t stream) {
    const float* x      = (const float*)d_in[0];
    const float* sheafW = (const float*)d_in[1];
    const float* linW   = (const float*)d_in[2];
    const float* linb   = (const float*)d_in[3];
    const int*   ei     = (const int*)d_in[4];

    int N  = in_sizes[0] / D;
    int E  = in_sizes[4] / 2;
    int E2 = E / 2;

    // Workspace layout (8B-aligned first):
    // diagcnt[N*PAD] u64 | pairs[E] int2 | y[N*D] f32 | a[N] b[N] | mm[E2] |
    // off[N+1] | dsi[N] diag[N] | bsum[256] | rank[E] u16
    char* wp = (char*)d_ws;
    unsigned long long* diagcnt = (unsigned long long*)wp; wp += (size_t)N * PAD * 8;
    int2*  pairs = (int2*)wp;  wp += (size_t)E * 8;
    float* y     = (float*)wp; wp += (size_t)N * D * 4;
    float* a     = (float*)wp; wp += (size_t)N * 4;
    float* b     = (float*)wp; wp += (size_t)N * 4;
    float* mm    = (float*)wp; wp += (size_t)E2 * 4;
    int*   off   = (int*)wp;   wp += (size_t)(N + 1) * 4;
    float* dsi   = (float*)wp; wp += (size_t)N * 4;
    float* diag  = (float*)wp; wp += (size_t)N * 4;
    int*   bsum  = (int*)wp;   wp += 256 * 4;
    unsigned short* rank = (unsigned short*)wp;

    float* out = (float*)d_out;

    hipMemsetAsync(diagcnt, 0, (size_t)N * PAD * sizeof(unsigned long long), stream);

    const int B = 256;
    int nbN  = (N + B - 1) / B;      // 196 for N=50000 (<=256 required by scan2)
    int nbE2 = (E2 + B - 1) / B;

    k_node_pre<<<nbN, B, 0, stream>>>(x, sheafW, linW, linb, a, b, y, N);
    k_edge_pass1<<<nbE2, B, 0, stream>>>(ei, a, b, diagcnt, rank, mm, E2, E);
    k_scan1<<<nbN, B, 0, stream>>>(diagcnt, off, bsum, N);
    k_scan2<<<1, B, 0, stream>>>(bsum, nbN);
    k_scan3<<<nbN, B, 0, stream>>>(off, bsum, diagcnt, dsi, diag, N, E);
    k_fill<<<nbE2, B, 0, stream>>>(ei, mm, dsi, off, rank, pairs, E2, E);
    k_gather<<<((size_t)N * D + B - 1) / B, B, 0, stream>>>(off, pairs, y, x, dsi, diag, out, N);
}

// Round 5
// 120.661 us; speedup vs baseline: 2.8391x; 1.4094x over previous
//
#include <hip/hip_runtime.h>

#define D 32
#define GBITS 7
#define GSIZE 128              // rows per group (1 << GBITS)
#define BLK 256
#define IPT 16                 // items per thread in hist/scatter
#define IPB (BLK * IPT)        // 4096 items per block

static __device__ __forceinline__ unsigned short f2h(float f) {
    _Float16 h = (_Float16)f;
    return __builtin_bit_cast(unsigned short, h);
}
static __device__ __forceinline__ float h2f(unsigned short u) {
    return (float)__builtin_bit_cast(_Float16, u);
}

// ---------------------------------------------------------------------------
// K1: per-node precompute.  ab[n] = (x[n].sheafW[0:D], x[n].sheafW[D:2D])
//     y[n,:] = lin_W @ x[n] + lin_b
// ---------------------------------------------------------------------------
__global__ void k_node_pre(const float* __restrict__ x,
                           const float* __restrict__ sheafW,
                           const float* __restrict__ linW,
                           const float* __restrict__ linb,
                           float2* __restrict__ ab,
                           float* __restrict__ y, int N) {
    __shared__ float sW[D * D];
    __shared__ float sB[D];
    __shared__ float sS[2 * D];
    for (int i = threadIdx.x; i < D * D; i += blockDim.x) sW[i] = linW[i];
    if (threadIdx.x < D) sB[threadIdx.x] = linb[threadIdx.x];
    if (threadIdx.x < 2 * D) sS[threadIdx.x] = sheafW[threadIdx.x];
    __syncthreads();

    int n = blockIdx.x * blockDim.x + threadIdx.x;
    if (n >= N) return;

    float xv[D];
    const float4* xp = reinterpret_cast<const float4*>(x + (size_t)n * D);
#pragma unroll
    for (int i = 0; i < D / 4; ++i) {
        float4 v = xp[i];
        xv[4 * i + 0] = v.x; xv[4 * i + 1] = v.y;
        xv[4 * i + 2] = v.z; xv[4 * i + 3] = v.w;
    }

    float av = 0.f, bv = 0.f;
#pragma unroll
    for (int d = 0; d < D; ++d) { av += xv[d] * sS[d]; bv += xv[d] * sS[D + d]; }
    ab[n] = make_float2(av, bv);

    float4* yp = reinterpret_cast<float4*>(y + (size_t)n * D);
#pragma unroll
    for (int j4 = 0; j4 < D / 4; ++j4) {
        float4 o;
#pragma unroll
        for (int jj = 0; jj < 4; ++jj) {
            int j = 4 * j4 + jj;
            float s = sB[j];
#pragma unroll
            for (int d = 0; d < D; ++d) s += xv[d] * sW[j * D + d];
            (&o.x)[jj] = s;
        }
        yp[j4] = o;
    }
}

// ---------------------------------------------------------------------------
// K2: per undirected pair -> two packed items (row<<48 | col<<32 | m16 | mr16)
// ---------------------------------------------------------------------------
__global__ void k_edge_items(const int* __restrict__ ei,
                             const float2* __restrict__ ab,
                             unsigned long long* __restrict__ items,
                             int E2, int E) {
    int i = blockIdx.x * blockDim.x + threadIdx.x;
    if (i >= E2) return;
    int s = ei[i];
    int t = ei[E + i];
    float2 as = ab[s], at = ab[t];
    float m  = tanhf(as.x + at.y);
    float mr = tanhf(at.x + as.y);
    unsigned long long hm = f2h(m), hmr = f2h(mr);
    items[i] = ((unsigned long long)(unsigned)s << 48) |
               ((unsigned long long)(unsigned)t << 32) | (hm << 16) | hmr;
    items[i + E2] = ((unsigned long long)(unsigned)t << 48) |
                    ((unsigned long long)(unsigned)s << 32) | (hmr << 16) | hm;
}

// ---------------------------------------------------------------------------
// K3: blocked histogram of bin = row >> GBITS.  bhist[bin * nblkH + blk].
// ---------------------------------------------------------------------------
__global__ void k_hist(const unsigned long long* __restrict__ items,
                       int* __restrict__ bhist, int E, int nblkH, int NBG) {
    __shared__ int hist[512];
    for (int i = threadIdx.x; i < NBG; i += BLK) hist[i] = 0;
    __syncthreads();
    int base = blockIdx.x * IPB;
#pragma unroll
    for (int k = 0; k < IPT; ++k) {
        int e = base + k * BLK + threadIdx.x;
        if (e < E) {
            int bin = (int)(items[e] >> (48 + GBITS));
            atomicAdd(&hist[bin], 1);
        }
    }
    __syncthreads();
    for (int i = threadIdx.x; i < NBG; i += BLK)
        bhist[(size_t)i * nblkH + blockIdx.x] = hist[i];
}

// ---------------------------------------------------------------------------
// Scan level A: 256-elem blocks, local exclusive in place + block sums.
// ---------------------------------------------------------------------------
__global__ void k_scanA(int* __restrict__ data, int* __restrict__ bsum, int M) {
    __shared__ int s[256];
    int t = threadIdx.x;
    int i = blockIdx.x * 256 + t;
    int v = (i < M) ? data[i] : 0;
    s[t] = v;
    __syncthreads();
#pragma unroll
    for (int o = 1; o < 256; o <<= 1) {
        int tmp = (t >= o) ? s[t - o] : 0;
        __syncthreads();
        s[t] += tmp;
        __syncthreads();
    }
    if (i < M) data[i] = s[t] - v;
    if (t == 255) bsum[blockIdx.x] = s[255];
}

// ---------------------------------------------------------------------------
// Scan level B: one 1024-thread block scans <=1024 block sums to exclusive.
// ---------------------------------------------------------------------------
__global__ void k_scanB(int* __restrict__ bsum, int NB) {
    __shared__ int s[1024];
    int t = threadIdx.x;
    int v = (t < NB) ? bsum[t] : 0;
    s[t] = v;
    __syncthreads();
#pragma unroll
    for (int o = 1; o < 1024; o <<= 1) {
        int tmp = (t >= o) ? s[t - o] : 0;
        __syncthreads();
        s[t] += tmp;
        __syncthreads();
    }
    if (t < NB) bsum[t] = s[t] - v;
}

// ---------------------------------------------------------------------------
// K7: scatter items into group-contiguous order via LDS cursors.
// ---------------------------------------------------------------------------
__global__ void k_bin_scatter(const unsigned long long* __restrict__ items,
                              const int* __restrict__ bhist,
                              const int* __restrict__ bsum,
                              unsigned long long* __restrict__ binned,
                              int E, int nblkH, int NBG) {
    __shared__ int cursor[512];
    for (int i = threadIdx.x; i < NBG; i += BLK) {
        int idx = i * nblkH + blockIdx.x;
        cursor[i] = bhist[idx] + bsum[idx >> 8];
    }
    __syncthreads();
    int base = blockIdx.x * IPB;
#pragma unroll
    for (int k = 0; k < IPT; ++k) {
        int e = base + k * BLK + threadIdx.x;
        if (e < E) {
            unsigned long long it = items[e];
            int bin = (int)(it >> (48 + GBITS));
            int pos = atomicAdd(&cursor[bin], 1);
            binned[pos] = it;
        }
    }
}

// ---------------------------------------------------------------------------
// K8: per-group (128 rows) counting sort + diag/dsi/off + z = dsi*y in place.
//     All atomics are LDS.  final_ may alias items.
// ---------------------------------------------------------------------------
__global__ void k_group(const unsigned long long* __restrict__ binned,
                        const int* __restrict__ bhist,
                        const int* __restrict__ bsum,
                        unsigned long long* __restrict__ final_,
                        int* __restrict__ off,
                        float* __restrict__ dsi,
                        float* __restrict__ diag2,
                        float* __restrict__ y,   // becomes z = dsi*y
                        int E, int nblkH, int NBG, int N) {
    __shared__ int rhist[GSIZE];
    __shared__ float rdiag[GSIZE];
    __shared__ int rbase[GSIZE];
    __shared__ int cur[GSIZE];
    __shared__ float sds[GSIZE];
    __shared__ int ss[GSIZE];
    __shared__ int sgs[2];
    int g = blockIdx.x;
    int t = threadIdx.x;
    if (t < GSIZE) { rhist[t] = 0; rdiag[t] = 0.f; }
    if (t == 0) {
        int i0 = g * nblkH;
        sgs[0] = bhist[i0] + bsum[i0 >> 8];
        int i1 = i0 + nblkH;
        sgs[1] = (g + 1 < NBG) ? (bhist[i1] + bsum[i1 >> 8]) : E;
    }
    __syncthreads();
    int gstart = sgs[0], gend = sgs[1];

    // phase A: row histogram + diag partial sums
    for (int k = gstart + t; k < gend; k += blockDim.x) {
        unsigned long long it = binned[k];
        int r = (int)(it >> 48) - (g << GBITS);
        float m = h2f((unsigned short)((it >> 16) & 0xFFFF));
        atomicAdd(&rhist[r], 1);
        atomicAdd(&rdiag[r], m * m);
    }
    __syncthreads();

    // phase B: exclusive scan of rhist (GSIZE bins; all threads hit barriers)
    int v = (t < GSIZE) ? rhist[t] : 0;
    if (t < GSIZE) ss[t] = v;
    __syncthreads();
#pragma unroll
    for (int o = 1; o < GSIZE; o <<= 1) {
        int tmp = 0;
        if (t < GSIZE && t >= o) tmp = ss[t - o];
        __syncthreads();
        if (t < GSIZE) ss[t] += tmp;
        __syncthreads();
    }
    if (t < GSIZE) {
        int ex = ss[t] - v;
        rbase[t] = ex;
        cur[t] = gstart + ex;
        int n = (g << GBITS) + t;
        if (n < N) {
            off[n] = gstart + ex;
            float dm = rdiag[t];
            float ds = rsqrtf(dm + 1.0f);
            dsi[n] = ds;
            diag2[n] = dm * ds;          // diag/dsi = dm*ds
            sds[t] = ds;
        }
    }
    if (g == NBG - 1 && t == 0) off[N] = E;
    __syncthreads();

    // phase B2: z = dsi * y for this group's rows
    int rowsInG = min(GSIZE, N - (g << GBITS));
    for (int idx = t; idx < rowsInG * D; idx += blockDim.x) {
        int r = idx >> 5;                 // D == 32
        size_t p = ((size_t)((g << GBITS) + r)) * D + (idx & 31);
        y[p] *= sds[r];
    }

    // phase C: counting-scatter to final row-sorted order
    for (int k = gstart + t; k < gend; k += blockDim.x) {
        unsigned long long it = binned[k];
        int r = (int)(it >> 48) - (g << GBITS);
        int pos = atomicAdd(&cur[r], 1);
        final_[pos] = it;
    }
}

// ---------------------------------------------------------------------------
// K10: gather + finalize. Half-wave (32 lanes == D) per node.
//      out = x - diag2[n]*z + dsi[n] * sum_k m*mr * z[col_k,:]
// ---------------------------------------------------------------------------
__global__ void k_gather(const int* __restrict__ off,
                         const unsigned long long* __restrict__ items,
                         const float* __restrict__ z,
                         const float* __restrict__ x,
                         const float* __restrict__ dsi,
                         const float* __restrict__ diag2,
                         float* __restrict__ out, int N) {
    int tt = blockIdx.x * blockDim.x + threadIdx.x;
    int n = tt >> 5;
    int lane = tt & 31;
    if (n >= N) return;
    int start = off[n];
    int end = off[n + 1];
    float acc = 0.f;
    int k = start;
    for (; k + 4 <= end; k += 4) {
        unsigned long long i0 = items[k + 0];
        unsigned long long i1 = items[k + 1];
        unsigned long long i2 = items[k + 2];
        unsigned long long i3 = items[k + 3];
        int c0 = (int)((i0 >> 32) & 0xFFFF);
        int c1 = (int)((i1 >> 32) & 0xFFFF);
        int c2 = (int)((i2 >> 32) & 0xFFFF);
        int c3 = (int)((i3 >> 32) & 0xFFFF);
        float v0 = z[c0 * D + lane];
        float v1 = z[c1 * D + lane];
        float v2 = z[c2 * D + lane];
        float v3 = z[c3 * D + lane];
        acc += h2f((unsigned short)((i0 >> 16) & 0xFFFF)) * h2f((unsigned short)(i0 & 0xFFFF)) * v0;
        acc += h2f((unsigned short)((i1 >> 16) & 0xFFFF)) * h2f((unsigned short)(i1 & 0xFFFF)) * v1;
        acc += h2f((unsigned short)((i2 >> 16) & 0xFFFF)) * h2f((unsigned short)(i2 & 0xFFFF)) * v2;
        acc += h2f((unsigned short)((i3 >> 16) & 0xFFFF)) * h2f((unsigned short)(i3 & 0xFFFF)) * v3;
    }
    for (; k < end; ++k) {
        unsigned long long it = items[k];
        int c = (int)((it >> 32) & 0xFFFF);
        acc += h2f((unsigned short)((it >> 16) & 0xFFFF)) * h2f((unsigned short)(it & 0xFFFF)) *
               z[c * D + lane];
    }
    out[tt] = x[tt] - diag2[n] * z[tt] + dsi[n] * acc;
}

extern "C" void kernel_launch(void* const* d_in, const int* in_sizes, int n_in,
                              void* d_out, int out_size, void* d_ws, size_t ws_size,
                              hipStream_t stream) {
    const float* x      = (const float*)d_in[0];
    const float* sheafW = (const float*)d_in[1];
    const float* linW   = (const float*)d_in[2];
    const float* linb   = (const float*)d_in[3];
    const int*   ei     = (const int*)d_in[4];

    int N  = in_sizes[0] / D;
    int E  = in_sizes[4] / 2;
    int E2 = E / 2;

    int NBG   = (N + GSIZE - 1) / GSIZE;        // 391 groups
    int nblkH = (E + IPB - 1) / IPB;            // 391 hist blocks
    int MH    = NBG * nblkH;                    // blocked-hist entries
    int nblkA = (MH + 255) / 256;               // scanA blocks (<=1024)

    // Workspace (8B aligned first):
    // items[E] u64 (aliases final) | binned[E] u64 | ab[N] float2 |
    // y[N*D] f32 | off[N+1] | dsi[N] | diag2[N] | bhist[MH] | bsumA[nblkA]
    char* wp = (char*)d_ws;
    unsigned long long* items  = (unsigned long long*)wp; wp += (size_t)E * 8;
    unsigned long long* binned = (unsigned long long*)wp; wp += (size_t)E * 8;
    float2* ab   = (float2*)wp; wp += (size_t)N * 8;
    float*  y    = (float*)wp;  wp += (size_t)N * D * 4;
    int*    off  = (int*)wp;    wp += (size_t)(N + 1) * 4;
    float*  dsi  = (float*)wp;  wp += (size_t)N * 4;
    float*  diag2= (float*)wp;  wp += (size_t)N * 4;
    int*    bhist= (int*)wp;    wp += (size_t)MH * 4;
    int*    bsumA= (int*)wp;    wp += (size_t)nblkA * 4;

    float* out = (float*)d_out;

    int nbN  = (N + BLK - 1) / BLK;
    int nbE2 = (E2 + BLK - 1) / BLK;

    k_node_pre<<<nbN, BLK, 0, stream>>>(x, sheafW, linW, linb, ab, y, N);
    k_edge_items<<<nbE2, BLK, 0, stream>>>(ei, ab, items, E2, E);
    k_hist<<<nblkH, BLK, 0, stream>>>(items, bhist, E, nblkH, NBG);
    k_scanA<<<nblkA, 256, 0, stream>>>(bhist, bsumA, MH);
    k_scanB<<<1, 1024, 0, stream>>>(bsumA, nblkA);
    k_bin_scatter<<<nblkH, BLK, 0, stream>>>(items, bhist, bsumA, binned, E, nblkH, NBG);
    k_group<<<NBG, 1024, 0, stream>>>(binned, bhist, bsumA, items /*=final*/, off,
                                      dsi, diag2, y, E, nblkH, NBG, N);
    k_gather<<<((size_t)N * D + BLK - 1) / BLK, BLK, 0, stream>>>(off, items, y, x,
                                                                 dsi, diag2, out, N);
}